// Round 9
// baseline (338.224 us; speedup 1.0000x reference)
//
#include <hip/hip_runtime.h>
#include <stdint.h>

#define LSEQ 2048
#define M_TOT 32768          // B*L
#define KDIM 2048            // 2H
#define NKT 64               // K tiles of 32
#define NCT 4                // col tiles of 256
#define NEG_INF_F (-10000000000.0f)

typedef _Float16 f16;
typedef f16 f16x4 __attribute__((ext_vector_type(4)));
typedef f16 f16x8 __attribute__((ext_vector_type(8)));
typedef float f32x4 __attribute__((ext_vector_type(4)));

// ---------------- ws layout ----------------
// [0, 64K)      sdec f32[16][1024]
// [64K, 576K)   part f32[4][32768]
// [2M, 6M)      we16 plain fp16 [1024][2048]
#define WS_SDEC_OFF  0
#define WS_PART_OFF  (64u << 10)
#define WS_WE16_OFF  (2u << 20)

// fast tanh(x)*s with sign fold
__device__ inline float tanh_mul(float x, float s) {
    float ax = __builtin_fabsf(x);
    float e  = __expf(-2.f * ax);
    float th = (1.f - e) * __builtin_amdgcn_rcpf(1.f + e);
    float sv = __uint_as_float(__float_as_uint(s) ^ (__float_as_uint(x) & 0x80000000u));
    return th * sv;
}

// W_e = attn_w[:, H:3H] -> plain fp16 [h][e]
__global__ void wecvt_kernel(const float* __restrict__ attn_w, f16* __restrict__ we16) {
    int idx = blockIdx.x * 256 + threadIdx.x;
    int h  = idx >> 9;
    int e4 = idx & 511;
    const float4 v4 = *reinterpret_cast<const float4*>(attn_w + (size_t)h * 3072 + 1024 + e4 * 4);
    f16x4 hv = { (f16)v4.x, (f16)v4.y, (f16)v4.z, (f16)v4.w };
    *reinterpret_cast<f16x4*>(we16 + (size_t)h * 2048 + e4 * 4) = hv;
}

// score_dec[b][h] = attn_b[h] + sum_k v[b][k] * attn_w[h][k]
__global__ void sdec_kernel(const float* __restrict__ v,
                            const float* __restrict__ attn_w,
                            const float* __restrict__ attn_b,
                            float* __restrict__ sdec) {
    int gid  = blockIdx.x * 4 + (threadIdx.x >> 6);
    int lane = threadIdx.x & 63;
    int b = gid >> 10;
    int h = gid & 1023;
    const float* vr = v + b * 1024;
    const float* wr = attn_w + (size_t)h * 3072;
    float s = 0.f;
    #pragma unroll 4
    for (int k = lane; k < 1024; k += 64) s += vr[k] * wr[k];
    #pragma unroll
    for (int m = 1; m < 64; m <<= 1) s += __shfl_xor(s, m);
    if (lane == 0) sdec[b * 1024 + h] = s + attn_b[h];
}

// Fused GEMM: 256x256 tile, 8 waves (2M x 4N), BK=32, 1 block/CU.
// A: fp32 global -> regs (compiler-tracked) -> cvt f16 -> swizzled LDS 3-ring.
// B: regs direct from we16 (L2/L3-resident), dbuf.
// 2 phases per K-tile, m201 rhythm: {ds_read||issue; BAR; lgkm0; 16 MFMA; BAR}.
__global__ __launch_bounds__(512, 2) void fused_gemm(
        const float* __restrict__ enc,   // [32768][2048] fp32
        const f16* __restrict__ we16,    // [1024][2048]
        const float* __restrict__ sdec,  // [16][1024]
        const float* __restrict__ vw,    // [1024]
        float* __restrict__ part)        // [NCT][32768]
{
    // chunked XCD remap: 512 blocks, 64 per XCD; siblings (same rt) adjacent
    const int logical = ((int)blockIdx.x & 7) * 64 + ((int)blockIdx.x >> 3);
    const int rt = logical >> 2;     // 0..127 (256-row tile)
    const int ct = logical & 3;      // 0..3   (256-col tile)

    const int tid = threadIdx.x;
    const int l15 = tid & 15;
    const int l4  = (tid >> 4) & 3;
    const int wv  = tid >> 6;        // 0..7
    const int wm  = wv >> 2;         // 0..1  (128 rows each)
    const int wn  = wv & 3;          // 0..3  (64 cols each)

    __shared__ char Abuf[3 * 16384]; // ring of 3 A K-tile bufs (256 rows x 64B)
    __shared__ float red[4][256];

    // ---- A staging: thread -> row r=tid&255, half h=tid>>8 (16 floats) ----
    const int r = tid & 255;
    const int h = tid >> 8;
    const float* aG = enc + (size_t)(rt * 256 + r) * KDIM + h * 16;
    // swizzled write byte offsets: slots 2h, 2h+1; phys = s ^ ((r>>1)&3)
    const int wb0 = r * 64 + ((((2 * h) ^ ((r >> 1) & 3))) << 4);
    const int wb1 = r * 64 + ((((2 * h + 1) ^ ((r >> 1) & 3))) << 4);

    // ---- fragment reads: row = wm*128 + i*16 + l15, phys slot = l4 ^ ((l15>>1)&3)
    const int sw  = (l4 ^ ((l15 >> 1) & 3)) << 4;
    const int aro = (wm * 128 + l15) * 64 + sw;          // + i*1024

    // B: bf[j] <- we16[ct*256 + wn*64 + j*16 + l15][t*32 + l4*8]
    const f16* bptr = we16 + (size_t)(ct * 256 + wn * 64 + l15) * KDIM + l4 * 8;

    f32x4 acc[8][4] = {};
    float4 sA[4], sB[4];
    f16x8 bA[4], bB[4];

    auto loadA = [&](float4 (&s)[4], int t) {
        const float* p = aG + t * 32;
        s[0] = *(const float4*)p;
        s[1] = *(const float4*)(p + 4);
        s[2] = *(const float4*)(p + 8);
        s[3] = *(const float4*)(p + 12);
    };
    auto loadB = [&](f16x8 (&b)[4], int t) {
        const f16* p = bptr + t * 32;
        #pragma unroll
        for (int j = 0; j < 4; ++j)
            b[j] = *(const f16x8*)(p + (size_t)j * 16 * KDIM);
    };
    auto writeA = [&](const float4 (&s)[4], int buf) {
        char* d = Abuf + buf * 16384;
        f16x8 h0 = { (f16)s[0].x, (f16)s[0].y, (f16)s[0].z, (f16)s[0].w,
                     (f16)s[1].x, (f16)s[1].y, (f16)s[1].z, (f16)s[1].w };
        f16x8 h1 = { (f16)s[2].x, (f16)s[2].y, (f16)s[2].z, (f16)s[2].w,
                     (f16)s[3].x, (f16)s[3].y, (f16)s[3].z, (f16)s[3].w };
        *(f16x8*)(d + wb0) = h0;
        *(f16x8*)(d + wb1) = h1;
    };

    int bufR = 0;
    auto body = [&](int t, float4 (&sN)[4], const float4 (&sC)[4],
                    f16x8 (&bC)[4], f16x8 (&bN)[4]) {
        const char* base = Abuf + bufR * 16384;
        const int bufW = (bufR == 2) ? 0 : bufR + 1;
        f16x8 fa[4];
        // ---------- phase 0 ----------
        #pragma unroll
        for (int i = 0; i < 4; ++i) fa[i] = *(const f16x8*)(base + aro + i * 1024);
        if (t + 1 < NKT) loadB(bN, t + 1);
        if (t + 2 < NKT) loadA(sN, t + 2);
        __builtin_amdgcn_sched_barrier(0);
        __builtin_amdgcn_s_barrier();
        asm volatile("s_waitcnt lgkmcnt(0)" ::: "memory");
        __builtin_amdgcn_sched_barrier(0);
        __builtin_amdgcn_s_setprio(1);
        #pragma unroll
        for (int i = 0; i < 4; ++i)
            #pragma unroll
            for (int j = 0; j < 4; ++j)
                acc[i][j] = __builtin_amdgcn_mfma_f32_16x16x32_f16(fa[i], bC[j], acc[i][j], 0, 0, 0);
        __builtin_amdgcn_s_setprio(0);
        __builtin_amdgcn_s_barrier();
        // ---------- phase 1 ----------
        #pragma unroll
        for (int i = 0; i < 4; ++i) fa[i] = *(const f16x8*)(base + aro + (4 + i) * 1024);
        if (t + 1 < NKT) writeA(sC, bufW);   // cvt waits A(t+1) regs (compiler vmcnt)
        __builtin_amdgcn_sched_barrier(0);
        __builtin_amdgcn_s_barrier();
        asm volatile("s_waitcnt lgkmcnt(0)" ::: "memory");
        __builtin_amdgcn_sched_barrier(0);
        __builtin_amdgcn_s_setprio(1);
        #pragma unroll
        for (int i = 0; i < 4; ++i)
            #pragma unroll
            for (int j = 0; j < 4; ++j)
                acc[4 + i][j] = __builtin_amdgcn_mfma_f32_16x16x32_f16(fa[i], bC[j], acc[4 + i][j], 0, 0, 0);
        __builtin_amdgcn_s_setprio(0);
        __builtin_amdgcn_s_barrier();
        bufR = bufW;
    };

    // ---- prologue: A(0)->buf0, A(1)->sB in flight, B(0)->bA ----
    loadA(sA, 0);
    loadB(bA, 0);
    loadA(sB, 1);
    writeA(sA, 0);                       // waits A(0) only (FIFO)
    asm volatile("s_waitcnt lgkmcnt(0)" ::: "memory");
    __builtin_amdgcn_s_barrier();
    __builtin_amdgcn_sched_barrier(0);

    #pragma unroll 1
    for (int tt = 0; tt < NKT; tt += 2) {
        body(tt,     sA, sB, bA, bB);    // consumes buf tt, B(tt); stages A(tt+2), writes A(tt+1)
        body(tt + 1, sB, sA, bB, bA);
    }

    // ---------------- epilogue ----------------
    // C/D frag: col = l15, row = l4*4 + r_; global row = rowbase + wm*128 + i*16 + l4*4 + r_
    const int rowbase = rt * 256;
    const int colbase = ct * 256;
    const int bidx = rt >> 3;

    float sd[4], vs[4];
    #pragma unroll
    for (int j = 0; j < 4; ++j) {
        const int col = colbase + wn * 64 + j * 16 + l15;
        sd[j] = sdec[bidx * 1024 + col];
        vs[j] = vw[col];
    }
    float psum[8][4] = {};
    #pragma unroll
    for (int i = 0; i < 8; ++i)
        #pragma unroll
        for (int j = 0; j < 4; ++j)
            #pragma unroll
            for (int q = 0; q < 4; ++q)
                psum[i][q] += tanh_mul(acc[i][j][q] + sd[j], vs[j]);

    #pragma unroll
    for (int i = 0; i < 8; ++i)
        #pragma unroll
        for (int q = 0; q < 4; ++q) {
            float s = psum[i][q];
            s += __shfl_xor(s, 1); s += __shfl_xor(s, 2);
            s += __shfl_xor(s, 4); s += __shfl_xor(s, 8);
            psum[i][q] = s;
        }

    __syncthreads();
    if (l15 == 0) {
        #pragma unroll
        for (int i = 0; i < 8; ++i)
            #pragma unroll
            for (int q = 0; q < 4; ++q)
                red[wn][wm * 128 + i * 16 + l4 * 4 + q] = psum[i][q];
    }
    __syncthreads();
    if (tid < 256)
        part[(size_t)ct * M_TOT + rowbase + tid] =
            red[0][tid] + red[1][tid] + red[2][tid] + red[3][tid];
}

// softmax over L per batch; mask==0 -> -1e10; sums the NCT partials.
__global__ __launch_bounds__(512) void softmax_kernel(
        const float* __restrict__ part, const int* __restrict__ mask,
        float* __restrict__ out) {
    int b = blockIdx.x;
    int tid = threadIdx.x;
    int lane = tid & 63, w = tid >> 6;
    __shared__ float sred[8];

    float vals[4];
    #pragma unroll
    for (int p = 0; p < 4; ++p) {
        int row = b * LSEQ + tid + p * 512;
        float val = 0.f;
        #pragma unroll
        for (int q = 0; q < NCT; ++q) val += part[(size_t)q * M_TOT + row];
        vals[p] = (mask[row] == 0) ? NEG_INF_F : val;
    }
    float mx = fmaxf(fmaxf(vals[0], vals[1]), fmaxf(vals[2], vals[3]));
    #pragma unroll
    for (int m = 1; m < 64; m <<= 1) mx = fmaxf(mx, __shfl_xor(mx, m));
    if (lane == 0) sred[w] = mx;
    __syncthreads();
    float gmax = sred[0];
    #pragma unroll
    for (int i = 1; i < 8; ++i) gmax = fmaxf(gmax, sred[i]);

    float es[4]; float ssum = 0.f;
    #pragma unroll
    for (int p = 0; p < 4; ++p) { es[p] = expf(vals[p] - gmax); ssum += es[p]; }
    #pragma unroll
    for (int m = 1; m < 64; m <<= 1) ssum += __shfl_xor(ssum, m);
    __syncthreads();
    if (lane == 0) sred[w] = ssum;
    __syncthreads();
    float gsum = 0.f;
    #pragma unroll
    for (int i = 0; i < 8; ++i) gsum += sred[i];
    float inv = 1.f / gsum;
    #pragma unroll
    for (int p = 0; p < 4; ++p)
        out[b * LSEQ + tid + p * 512] = es[p] * inv;
}

extern "C" void kernel_launch(void* const* d_in, const int* in_sizes, int n_in,
                              void* d_out, int out_size, void* d_ws, size_t ws_size,
                              hipStream_t stream) {
    const float* enc    = (const float*)d_in[0];
    const int*   mask   = (const int*)  d_in[1];
    const float* v      = (const float*)d_in[2];
    const float* attn_w = (const float*)d_in[3];
    const float* attn_b = (const float*)d_in[4];
    const float* v_w    = (const float*)d_in[5];
    float* out = (float*)d_out;

    char* ws = (char*)d_ws;
    float* sdec = (float*)(ws + WS_SDEC_OFF);
    float* part = (float*)(ws + WS_PART_OFF);
    f16*   we16 = (f16*)  (ws + WS_WE16_OFF);

    hipLaunchKernelGGL(wecvt_kernel, dim3(2048), dim3(256), 0, stream, attn_w, we16);
    hipLaunchKernelGGL(sdec_kernel,  dim3(4096), dim3(256), 0, stream, v, attn_w, attn_b, sdec);
    hipLaunchKernelGGL(fused_gemm,   dim3(512),  dim3(512), 0, stream,
                       enc, we16, sdec, v_w, part);
    hipLaunchKernelGGL(softmax_kernel, dim3(16), dim3(512), 0, stream, part, mask, out);
}

// Round 10
// 223.507 us; speedup vs baseline: 1.5133x; 1.5133x over previous
//
#include <hip/hip_runtime.h>
#include <stdint.h>

#define LSEQ 2048
#define M_TOT 32768          // B*L
#define KDIM 2048            // 2H
#define NKT 64               // K tiles of 32
#define NCT 4                // col tiles of 256
#define NEG_INF_F (-10000000000.0f)

typedef _Float16 f16;
typedef f16 f16x4 __attribute__((ext_vector_type(4)));
typedef f16 f16x8 __attribute__((ext_vector_type(8)));
typedef float f32x4 __attribute__((ext_vector_type(4)));

// ---------------- ws layout ----------------
// [0, 64K)      sdec f32[16][1024]
// [64K, 576K)   part f32[4][32768]
// [2M, 6M)      weT  tiled fp16 B [4 ct][64 kt][1024 granules x 16B]
// [6M, ...)     encT tiled fp16 A [rtl][64 kt][1024 granules x 16B] (chunked)
#define WS_SDEC_OFF  0
#define WS_PART_OFF  (64u << 10)
#define WS_WET_OFF   (2u << 20)
#define WS_ENCT_OFF  (6u << 20)

__device__ inline void gload16(const void* g, void* l) {
    __builtin_amdgcn_global_load_lds(
        (const __attribute__((address_space(1))) void*)g,
        (__attribute__((address_space(3))) void*)l, 16, 0, 0);
}

// fast tanh(x)*s with sign fold
__device__ inline float tanh_mul(float x, float s) {
    float ax = __builtin_fabsf(x);
    float e  = __expf(-2.f * ax);
    float th = (1.f - e) * __builtin_amdgcn_rcpf(1.f + e);
    float sv = __uint_as_float(__float_as_uint(s) ^ (__float_as_uint(x) & 0x80000000u));
    return th * sv;
}

// W_e -> tiled fp16 B, 0-conflict swizzle: granule g: ct=g>>16, kt=(g>>10)&63,
// p=g&1023, row=p>>2, sl=(p&3)^((row>>1)&3). 256 blocks x 256 thr x 4.
__global__ __launch_bounds__(256) void wecvt_tiled(const float* __restrict__ attn_w,
                                                   f16* __restrict__ weT) {
    int g = blockIdx.x * 1024 + threadIdx.x;
    #pragma unroll
    for (int q = 0; q < 4; ++q, g += 256) {
        int ct  = g >> 16;
        int rem = g & 65535;
        int kt  = rem >> 10;
        int p   = rem & 1023;
        int row = p >> 2;
        int sl  = (p & 3) ^ ((row >> 1) & 3);
        const float* s = attn_w + (size_t)(ct * 256 + row) * 3072 + 1024 + kt * 32 + sl * 8;
        float4 a = *(const float4*)s;
        float4 b = *(const float4*)(s + 4);
        f16x8 h = { (f16)a.x,(f16)a.y,(f16)a.z,(f16)a.w,(f16)b.x,(f16)b.y,(f16)b.z,(f16)b.w };
        *(f16x8*)(weT + (size_t)g * 8) = h;
    }
}

// encoder_out -> tiled fp16 A (one chunk of rts row-tiles), same swizzle.
__global__ __launch_bounds__(256) void enccvt(const float* __restrict__ enc,
                                              f16* __restrict__ encT, int rt0) {
    int g = blockIdx.x * 2048 + threadIdx.x;
    #pragma unroll
    for (int q = 0; q < 8; ++q, g += 256) {
        int rtl = g >> 16;
        int rem = g & 65535;
        int kt  = rem >> 10;
        int p   = rem & 1023;
        int row = p >> 2;
        int sl  = (p & 3) ^ ((row >> 1) & 3);
        const float* s = enc + (size_t)((rt0 + rtl) * 256 + row) * 2048 + kt * 32 + sl * 8;
        float4 a = *(const float4*)s;
        float4 b = *(const float4*)(s + 4);
        f16x8 h = { (f16)a.x,(f16)a.y,(f16)a.z,(f16)a.w,(f16)b.x,(f16)b.y,(f16)b.z,(f16)b.w };
        *(f16x8*)(encT + (size_t)g * 8) = h;
    }
}

// score_dec[b][h] = attn_b[h] + sum_k v[b][k] * attn_w[h][k]
__global__ void sdec_kernel(const float* __restrict__ v,
                            const float* __restrict__ attn_w,
                            const float* __restrict__ attn_b,
                            float* __restrict__ sdec) {
    int gid  = blockIdx.x * 4 + (threadIdx.x >> 6);
    int lane = threadIdx.x & 63;
    int b = gid >> 10;
    int h = gid & 1023;
    const float* vr = v + b * 1024;
    const float* wr = attn_w + (size_t)h * 3072;
    float s = 0.f;
    #pragma unroll 4
    for (int k = lane; k < 1024; k += 64) s += vr[k] * wr[k];
    #pragma unroll
    for (int m = 1; m < 64; m <<= 1) s += __shfl_xor(s, m);
    if (lane == 0) sdec[b * 1024 + h] = s + attn_b[h];
}

#define PH_OPEN  do { __builtin_amdgcn_sched_barrier(0); __builtin_amdgcn_s_barrier(); \
                      asm volatile("s_waitcnt lgkmcnt(0)" ::: "memory"); \
                      __builtin_amdgcn_sched_barrier(0); } while (0)
#define PH_CLOSE do { __builtin_amdgcn_sched_barrier(0); __builtin_amdgcn_s_barrier(); } while (0)

// GEMM: 256x256 tile, 8 waves (2M x 4N), BK=32, 1 block/CU.
// m201-faithful: 4-slot LDS ring (A16K+B16K), 4 phases per 2 K-tiles, each
// {ds_reads || 2 gloads; BAR; lgkm0; setprio1; 16 MFMA; setprio0; BAR};
// single counted vmcnt(2) per iteration (never 0 until tail).
__global__ __launch_bounds__(512, 2) void fused_gemm(
        const f16* __restrict__ encT,   // [rtl][64 kt][16KB]
        const f16* __restrict__ weT,    // [4 ct][64 kt][16KB]
        const float* __restrict__ sdec, // [16][1024]
        const float* __restrict__ vw,   // [1024]
        float* __restrict__ part,       // [NCT][32768]
        int rt0, int nblocks)
{
    // chunked XCD remap (nblocks % 8 == 0); siblings (same rtl) adjacent
    const int cpx = nblocks >> 3;
    const int logical = ((int)blockIdx.x & 7) * cpx + ((int)blockIdx.x >> 3);
    const int rtl = logical >> 2;
    const int ct  = logical & 3;

    const int tid = threadIdx.x;
    const int l15 = tid & 15;
    const int l4  = (tid >> 4) & 3;
    const int wv  = tid >> 6;        // 0..7
    const int wm  = wv >> 2;         // 0..1  (128 rows each)
    const int wn  = wv & 3;          // 0..3  (64 cols each)

    __shared__ char lds[4 * 32768];  // ring: slot = kt&3, [A 16KB | B 16KB]
    __shared__ float red[4][256];

    const char* aT = (const char*)encT + ((size_t)rtl << 20);
    const char* bT = (const char*)weT  + ((size_t)ct  << 20);

    // fragment offsets: row stride 64B, phys slot = l4 ^ ((row>>1)&3), row%16==l15
    const int swz = (l4 ^ ((l15 >> 1) & 3)) << 4;
    const int aro = (wm * 128 + l15) * 64 + swz;           // + i*1024
    const int bro = 16384 + (wn * 64 + l15) * 64 + swz;    // + j*1024

    f32x4 acc[8][4] = {};

    auto stageA = [&](int t) {
        const char* s = aT + ((size_t)t << 14) + tid * 16;
        char* d = lds + ((t & 3) << 15) + tid * 16;
        gload16(s, d); gload16(s + 8192, d + 8192);
    };
    auto stageB = [&](int t) {
        const char* s = bT + ((size_t)t << 14) + tid * 16;
        char* d = lds + ((t & 3) << 15) + 16384 + tid * 16;
        gload16(s, d); gload16(s + 8192, d + 8192);
    };
    auto RA = [&](f16x8 (&fa)[4], int sbase, int ih) {
        const char* p = lds + sbase + aro + ih * 4096;
        #pragma unroll
        for (int ii = 0; ii < 4; ++ii) fa[ii] = *(const f16x8*)(p + ii * 1024);
    };
    auto RB = [&](f16x8 (&bf)[4], int sbase) {
        const char* p = lds + sbase + bro;
        #pragma unroll
        for (int j = 0; j < 4; ++j) bf[j] = *(const f16x8*)(p + j * 1024);
    };

    // ---- prologue: A0,B0,A1,B1,A2 issued; drain through B1 (tiles 0,1 valid) ----
    stageA(0); stageB(0); stageA(1); stageB(1); stageA(2);
    asm volatile("s_waitcnt vmcnt(2)" ::: "memory");
    __builtin_amdgcn_s_barrier();
    __builtin_amdgcn_sched_barrier(0);

    #pragma unroll 1
    for (int tt = 0; tt < NKT; tt += 2) {
        const int s0 = (tt & 3) << 15;
        const int s1 = ((tt + 1) & 3) << 15;
        f16x8 fa[4], bf[4];
        // -------- phase 0: kstep tt, i=0..3 --------
        RA(fa, s0, 0); RB(bf, s0);
        if (tt + 2 < NKT) stageB(tt + 2);
        PH_OPEN;
        __builtin_amdgcn_s_setprio(1);
        #pragma unroll
        for (int ii = 0; ii < 4; ++ii)
            #pragma unroll
            for (int j = 0; j < 4; ++j)
                acc[ii][j] = __builtin_amdgcn_mfma_f32_16x16x32_f16(fa[ii], bf[j], acc[ii][j], 0, 0, 0);
        __builtin_amdgcn_s_setprio(0);
        PH_CLOSE;
        // -------- phase 1: kstep tt, i=4..7 --------
        RA(fa, s0, 1);
        if (tt + 3 < NKT) stageA(tt + 3);
        PH_OPEN;
        __builtin_amdgcn_s_setprio(1);
        #pragma unroll
        for (int ii = 0; ii < 4; ++ii)
            #pragma unroll
            for (int j = 0; j < 4; ++j)
                acc[4 + ii][j] = __builtin_amdgcn_mfma_f32_16x16x32_f16(fa[ii], bf[j], acc[4 + ii][j], 0, 0, 0);
        __builtin_amdgcn_s_setprio(0);
        PH_CLOSE;
        // -------- phase 2: kstep tt+1, i=0..3 --------
        RA(fa, s1, 0); RB(bf, s1);
        if (tt + 3 < NKT) stageB(tt + 3);
        PH_OPEN;
        __builtin_amdgcn_s_setprio(1);
        #pragma unroll
        for (int ii = 0; ii < 4; ++ii)
            #pragma unroll
            for (int j = 0; j < 4; ++j)
                acc[ii][j] = __builtin_amdgcn_mfma_f32_16x16x32_f16(fa[ii], bf[j], acc[ii][j], 0, 0, 0);
        __builtin_amdgcn_s_setprio(0);
        PH_CLOSE;
        // -------- phase 3: kstep tt+1, i=4..7 --------
        RA(fa, s1, 1);
        if (tt + 4 < NKT) stageA(tt + 4);
        PH_OPEN;
        __builtin_amdgcn_s_setprio(1);
        #pragma unroll
        for (int ii = 0; ii < 4; ++ii)
            #pragma unroll
            for (int j = 0; j < 4; ++j)
                acc[4 + ii][j] = __builtin_amdgcn_mfma_f32_16x16x32_f16(fa[ii], bf[j], acc[4 + ii][j], 0, 0, 0);
        __builtin_amdgcn_s_setprio(0);
        // counted vmcnt: tiles tt+2,tt+3 must be valid at next iteration;
        // leaves A(tt+4)'s 2 loads in flight. Tail: drain.
        if (tt < NKT - 4) { asm volatile("s_waitcnt vmcnt(2)" ::: "memory"); }
        else              { asm volatile("s_waitcnt vmcnt(0)" ::: "memory"); }
        PH_CLOSE;
    }

    // ---------------- epilogue ----------------
    // C/D frag: col = l15, row = l4*4 + q; global row = rowbase + wm*128 + i*16 + l4*4 + q
    const int rowbase = (rt0 + rtl) * 256;
    const int colbase = ct * 256;
    const int bidx = (rt0 + rtl) >> 3;

    float sd[4], vs[4];
    #pragma unroll
    for (int j = 0; j < 4; ++j) {
        const int col = colbase + wn * 64 + j * 16 + l15;
        sd[j] = sdec[bidx * 1024 + col];
        vs[j] = vw[col];
    }
    float psum[8][4] = {};
    #pragma unroll
    for (int i = 0; i < 8; ++i)
        #pragma unroll
        for (int j = 0; j < 4; ++j)
            #pragma unroll
            for (int q = 0; q < 4; ++q)
                psum[i][q] += tanh_mul(acc[i][j][q] + sd[j], vs[j]);

    #pragma unroll
    for (int i = 0; i < 8; ++i)
        #pragma unroll
        for (int q = 0; q < 4; ++q) {
            float s = psum[i][q];
            s += __shfl_xor(s, 1); s += __shfl_xor(s, 2);
            s += __shfl_xor(s, 4); s += __shfl_xor(s, 8);
            psum[i][q] = s;
        }

    __syncthreads();
    if (l15 == 0) {
        #pragma unroll
        for (int i = 0; i < 8; ++i)
            #pragma unroll
            for (int q = 0; q < 4; ++q)
                red[wn][wm * 128 + i * 16 + l4 * 4 + q] = psum[i][q];
    }
    __syncthreads();
    if (tid < 256)
        part[(size_t)ct * M_TOT + rowbase + tid] =
            red[0][tid] + red[1][tid] + red[2][tid] + red[3][tid];
}

// softmax over L per batch; mask==0 -> -1e10; sums the NCT partials.
__global__ __launch_bounds__(512) void softmax_kernel(
        const float* __restrict__ part, const int* __restrict__ mask,
        float* __restrict__ out) {
    int b = blockIdx.x;
    int tid = threadIdx.x;
    int lane = tid & 63, w = tid >> 6;
    __shared__ float sred[8];

    float vals[4];
    #pragma unroll
    for (int p = 0; p < 4; ++p) {
        int row = b * LSEQ + tid + p * 512;
        float val = 0.f;
        #pragma unroll
        for (int q = 0; q < NCT; ++q) val += part[(size_t)q * M_TOT + row];
        vals[p] = (mask[row] == 0) ? NEG_INF_F : val;
    }
    float mx = fmaxf(fmaxf(vals[0], vals[1]), fmaxf(vals[2], vals[3]));
    #pragma unroll
    for (int m = 1; m < 64; m <<= 1) mx = fmaxf(mx, __shfl_xor(mx, m));
    if (lane == 0) sred[w] = mx;
    __syncthreads();
    float gmax = sred[0];
    #pragma unroll
    for (int i = 1; i < 8; ++i) gmax = fmaxf(gmax, sred[i]);

    float es[4]; float ssum = 0.f;
    #pragma unroll
    for (int p = 0; p < 4; ++p) { es[p] = expf(vals[p] - gmax); ssum += es[p]; }
    #pragma unroll
    for (int m = 1; m < 64; m <<= 1) ssum += __shfl_xor(ssum, m);
    __syncthreads();
    if (lane == 0) sred[w] = ssum;
    __syncthreads();
    float gsum = 0.f;
    #pragma unroll
    for (int i = 0; i < 8; ++i) gsum += sred[i];
    float inv = 1.f / gsum;
    #pragma unroll
    for (int p = 0; p < 4; ++p)
        out[b * LSEQ + tid + p * 512] = es[p] * inv;
}

extern "C" void kernel_launch(void* const* d_in, const int* in_sizes, int n_in,
                              void* d_out, int out_size, void* d_ws, size_t ws_size,
                              hipStream_t stream) {
    const float* enc    = (const float*)d_in[0];
    const int*   mask   = (const int*)  d_in[1];
    const float* v      = (const float*)d_in[2];
    const float* attn_w = (const float*)d_in[3];
    const float* attn_b = (const float*)d_in[4];
    const float* v_w    = (const float*)d_in[5];
    float* out = (float*)d_out;

    char* ws = (char*)d_ws;
    float* sdec = (float*)(ws + WS_SDEC_OFF);
    float* part = (float*)(ws + WS_PART_OFF);
    f16*   weT  = (f16*)  (ws + WS_WET_OFF);
    f16*   encT = (f16*)  (ws + WS_ENCT_OFF);

    hipLaunchKernelGGL(wecvt_tiled, dim3(256),  dim3(256), 0, stream, attn_w, weT);
    hipLaunchKernelGGL(sdec_kernel, dim3(4096), dim3(256), 0, stream, v, attn_w, attn_b, sdec);

    // row-chunking: each row-tile (256 rows) needs 1 MB of encT; keep rts even
    size_t cap = (ws_size > WS_ENCT_OFF) ? (ws_size - WS_ENCT_OFF) : 0;
    int crt = (int)(cap >> 20);
    if (crt > 128) crt = 128;
    crt &= ~1;
    if (crt < 2) crt = 2;
    for (int rt0 = 0; rt0 < 128; rt0 += crt) {
        int rts = (128 - rt0 < crt) ? (128 - rt0) : crt;
        hipLaunchKernelGGL(enccvt,     dim3(rts * 32), dim3(256), 0, stream, enc, encT, rt0);
        hipLaunchKernelGGL(fused_gemm, dim3(rts * 4),  dim3(512), 0, stream,
                           encT, weT, sdec, v_w, part, rt0, rts * 4);
    }
    hipLaunchKernelGGL(softmax_kernel, dim3(16), dim3(512), 0, stream, part, mask, out);
}

// Round 12
// 215.439 us; speedup vs baseline: 1.5699x; 1.0375x over previous
//
#include <hip/hip_runtime.h>
#include <stdint.h>

#define LSEQ 2048
#define M_TOT 32768          // B*L
#define KDIM 2048            // 2H
#define NKT 64               // K tiles of 32
#define NCT 4                // col tiles of 256
#define NEG_INF_F (-10000000000.0f)

typedef _Float16 f16;
typedef f16 f16x8 __attribute__((ext_vector_type(8)));
typedef float f32x4 __attribute__((ext_vector_type(4)));

// ---------------- ws layout ----------------
// [0, 64K)      sdec f32[16][1024]
// [64K, 576K)   part f32[4][32768]
// [2M, 6M)      weT  tiled fp16 B [4 ct][64 kt][1024 granules x 16B]
#define WS_SDEC_OFF  0
#define WS_PART_OFF  (64u << 10)
#define WS_WET_OFF   (2u << 20)

#define SLOT_BYTES 49152     // A 32KB fp32 + B 16KB f16
#define BOFF 32768

__device__ inline void gload16(const void* g, void* l) {
    __builtin_amdgcn_global_load_lds(
        (const __attribute__((address_space(1))) void*)g,
        (__attribute__((address_space(3))) void*)l, 16, 0, 0);
}

// fast tanh(x)*s with sign fold
__device__ inline float tanh_mul(float x, float s) {
    float ax = __builtin_fabsf(x);
    float e  = __expf(-2.f * ax);
    float th = (1.f - e) * __builtin_amdgcn_rcpf(1.f + e);
    float sv = __uint_as_float(__float_as_uint(s) ^ (__float_as_uint(x) & 0x80000000u));
    return th * sv;
}

// W_e -> tiled fp16 B, 0-conflict swizzle (r5-verified): granule g: ct=g>>16,
// kt=(g>>10)&63, p=g&1023, row=p>>2, sl=(p&3)^((row>>1)&3).
__global__ __launch_bounds__(256) void wecvt_tiled(const float* __restrict__ attn_w,
                                                   f16* __restrict__ weT) {
    int g = blockIdx.x * 1024 + threadIdx.x;
    #pragma unroll
    for (int q = 0; q < 4; ++q, g += 256) {
        int ct  = g >> 16;
        int rem = g & 65535;
        int kt  = rem >> 10;
        int p   = rem & 1023;
        int row = p >> 2;
        int sl  = (p & 3) ^ ((row >> 1) & 3);
        const float* s = attn_w + (size_t)(ct * 256 + row) * 3072 + 1024 + kt * 32 + sl * 8;
        float4 a = *(const float4*)s;
        float4 b = *(const float4*)(s + 4);
        f16x8 h = { (f16)a.x,(f16)a.y,(f16)a.z,(f16)a.w,(f16)b.x,(f16)b.y,(f16)b.z,(f16)b.w };
        *(f16x8*)(weT + (size_t)g * 8) = h;
    }
}

// score_dec[b][h] = attn_b[h] + sum_k v[b][k] * attn_w[h][k]
__global__ void sdec_kernel(const float* __restrict__ v,
                            const float* __restrict__ attn_w,
                            const float* __restrict__ attn_b,
                            float* __restrict__ sdec) {
    int gid  = blockIdx.x * 4 + (threadIdx.x >> 6);
    int lane = threadIdx.x & 63;
    int b = gid >> 10;
    int h = gid & 1023;
    const float* vr = v + b * 1024;
    const float* wr = attn_w + (size_t)h * 3072;
    float s = 0.f;
    #pragma unroll 4
    for (int k = lane; k < 1024; k += 64) s += vr[k] * wr[k];
    #pragma unroll
    for (int m = 1; m < 64; m <<= 1) s += __shfl_xor(s, m);
    if (lane == 0) sdec[b * 1024 + h] = s + attn_b[h];
}

#define PH_OPEN  do { __builtin_amdgcn_sched_barrier(0); __builtin_amdgcn_s_barrier(); \
                      asm volatile("s_waitcnt lgkmcnt(0)" ::: "memory"); \
                      __builtin_amdgcn_sched_barrier(0); } while (0)
#define PH_CLOSE do { __builtin_amdgcn_sched_barrier(0); __builtin_amdgcn_s_barrier(); } while (0)

// ONE-PASS GEMM: 256x256 tile, 8 waves (2M x 4N), BK=32, 1 block/CU.
// A: raw fp32 enc staged via gload_lds with SWIZZLED PER-LANE SOURCE (no
//    pre-pass), 3-slot 48KB ring; read as b128 pairs; cvt_pkrtz -> f16 frags.
// B: pre-tiled weT f16 via gload_lds.
// 2 phases/K-tile {ds_reads || stage; BAR; lgkm0; cvt; 16 MFMA; BAR};
// counted vmcnt(6) once per K-tile.
__global__ __launch_bounds__(512, 2) void fused_gemm(
        const float* __restrict__ enc,  // [32768][2048] fp32
        const f16* __restrict__ weT,    // [4 ct][64 kt][16KB]
        const float* __restrict__ sdec, // [16][1024]
        const float* __restrict__ vw,   // [1024]
        float* __restrict__ part)       // [NCT][32768]
{
    // chunked XCD remap: 512 blocks, 64/XCD; 4 ct-siblings of one rt adjacent
    const int logical = ((int)blockIdx.x & 7) * 64 + ((int)blockIdx.x >> 3);
    const int rt = logical >> 2;
    const int ct = logical & 3;

    const int tid = threadIdx.x;
    const int l15 = tid & 15;
    const int l4  = (tid >> 4) & 3;
    const int wv  = tid >> 6;        // 0..7
    const int wm  = wv >> 2;         // 0..1  (128 rows each)
    const int wn  = wv & 3;          // 0..3  (64 cols each)

    __shared__ char lds[3 * SLOT_BYTES];   // 147456 B
    __shared__ float red[4][256];

    const int rowbase = rt * 256;
    const char* bT = (const char*)weT + ((size_t)ct << 20);

    // ---- A staging: thread -> row (tid>>3)+64c, phys slot tid&7 ----
    // source logical slot = phys ^ ((row>>1)&3); (row>>1)&3 = (tid>>4)&3 (c-invariant)
    const int slA = (tid & 7) ^ ((tid >> 4) & 3);
    const float* aG = enc + (size_t)(rowbase + (tid >> 3)) * KDIM + slA * 4;

    // ---- A frag reads: row = wm*128 + i*16 + l15; phys0 = (2l4)^((l15>>1)&3)
    const int aoffB = (wm * 128 + l15) * 128 + ((((2 * l4) ^ ((l15 >> 1) & 3))) << 4);
    // ---- B frag reads (r10 layout): row 64B, phys = l4^((row>>1)&3)
    const int bro = BOFF + (wn * 64 + l15) * 64 + ((l4 ^ ((l15 >> 1) & 3)) << 4);

    f32x4 acc[8][4] = {};

    auto stageA = [&](int t, int slot) {
        const float* s = aG + (size_t)t * 32;
        char* d = lds + slot * SLOT_BYTES + tid * 16;
        gload16(s,              d);
        gload16(s +  64 * KDIM, d + 8192);
        gload16(s + 128 * KDIM, d + 16384);
        gload16(s + 192 * KDIM, d + 24576);
    };
    auto stageB = [&](int t, int slot) {
        const char* s = bT + ((size_t)t << 14) + tid * 16;
        char* d = lds + slot * SLOT_BYTES + BOFF + tid * 16;
        gload16(s, d); gload16(s + 8192, d + 8192);
    };
    auto mk = [](const float4& a, const float4& b) -> f16x8 {
        auto c0 = __builtin_amdgcn_cvt_pkrtz(a.x, a.y);
        auto c1 = __builtin_amdgcn_cvt_pkrtz(a.z, a.w);
        auto c2 = __builtin_amdgcn_cvt_pkrtz(b.x, b.y);
        auto c3 = __builtin_amdgcn_cvt_pkrtz(b.z, b.w);
        f16x8 r = { (f16)c0[0], (f16)c0[1], (f16)c1[0], (f16)c1[1],
                    (f16)c2[0], (f16)c2[1], (f16)c3[0], (f16)c3[1] };
        return r;
    };

    // ---- prologue: tiles 0,1 staged; drain tile 0 ----
    stageA(0, 0); stageB(0, 0);
    stageA(1, 1); stageB(1, 1);
    asm volatile("s_waitcnt vmcnt(6)" ::: "memory");
    __builtin_amdgcn_s_barrier();
    __builtin_amdgcn_sched_barrier(0);

    int rb = 0, sw = 2;   // read slot t%3, stage slot (t+2)%3
    #pragma unroll 1
    for (int t = 0; t < NKT; ++t) {
        const char* sb = lds + rb * SLOT_BYTES;
        float4 ra[4], rb4[4];
        f16x8 bf[4], fa[4];
        // ---------- phase 0: i=0..3 ----------
        #pragma unroll
        for (int ii = 0; ii < 4; ++ii) {
            const int o = aoffB + ii * 2048;
            ra[ii]  = *(const float4*)(sb + o);
            rb4[ii] = *(const float4*)(sb + (o ^ 16));
        }
        #pragma unroll
        for (int j = 0; j < 4; ++j) bf[j] = *(const f16x8*)(sb + bro + j * 1024);
        if (t + 2 < NKT) stageB(t + 2, sw);
        PH_OPEN;
        #pragma unroll
        for (int ii = 0; ii < 4; ++ii) fa[ii] = mk(ra[ii], rb4[ii]);
        __builtin_amdgcn_s_setprio(1);
        #pragma unroll
        for (int ii = 0; ii < 4; ++ii)
            #pragma unroll
            for (int j = 0; j < 4; ++j)
                acc[ii][j] = __builtin_amdgcn_mfma_f32_16x16x32_f16(fa[ii], bf[j], acc[ii][j], 0, 0, 0);
        __builtin_amdgcn_s_setprio(0);
        PH_CLOSE;
        // ---------- phase 1: i=4..7 ----------
        #pragma unroll
        for (int ii = 0; ii < 4; ++ii) {
            const int o = aoffB + (4 + ii) * 2048;
            ra[ii]  = *(const float4*)(sb + o);
            rb4[ii] = *(const float4*)(sb + (o ^ 16));
        }
        if (t + 2 < NKT) stageA(t + 2, sw);
        PH_OPEN;
        #pragma unroll
        for (int ii = 0; ii < 4; ++ii) fa[ii] = mk(ra[ii], rb4[ii]);
        __builtin_amdgcn_s_setprio(1);
        #pragma unroll
        for (int ii = 0; ii < 4; ++ii)
            #pragma unroll
            for (int j = 0; j < 4; ++j)
                acc[4 + ii][j] = __builtin_amdgcn_mfma_f32_16x16x32_f16(fa[ii], bf[j], acc[4 + ii][j], 0, 0, 0);
        __builtin_amdgcn_s_setprio(0);
        // counted vmcnt: tile t+1 must be fully landed for next iter;
        // leaves tile t+2's 6 loads in flight.
        if (t < NKT - 2) { asm volatile("s_waitcnt vmcnt(6)" ::: "memory"); }
        else             { asm volatile("s_waitcnt vmcnt(0)" ::: "memory"); }
        PH_CLOSE;
        rb = (rb == 2) ? 0 : rb + 1;
        sw = (sw == 2) ? 0 : sw + 1;
    }

    // ---------------- epilogue ----------------
    // C/D frag: col = l15, row = l4*4 + q; global row = rowbase + wm*128 + i*16 + l4*4 + q
    const int colbase = ct * 256;
    const int bidx = rt >> 3;

    float sd[4], vs[4];
    #pragma unroll
    for (int j = 0; j < 4; ++j) {
        const int col = colbase + wn * 64 + j * 16 + l15;
        sd[j] = sdec[bidx * 1024 + col];
        vs[j] = vw[col];
    }
    float psum[8][4] = {};
    #pragma unroll
    for (int i = 0; i < 8; ++i)
        #pragma unroll
        for (int j = 0; j < 4; ++j)
            #pragma unroll
            for (int q = 0; q < 4; ++q)
                psum[i][q] += tanh_mul(acc[i][j][q] + sd[j], vs[j]);

    #pragma unroll
    for (int i = 0; i < 8; ++i)
        #pragma unroll
        for (int q = 0; q < 4; ++q) {
            float s = psum[i][q];
            s += __shfl_xor(s, 1); s += __shfl_xor(s, 2);
            s += __shfl_xor(s, 4); s += __shfl_xor(s, 8);
            psum[i][q] = s;
        }

    __syncthreads();
    if (l15 == 0) {
        #pragma unroll
        for (int i = 0; i < 8; ++i)
            #pragma unroll
            for (int q = 0; q < 4; ++q)
                red[wn][wm * 128 + i * 16 + l4 * 4 + q] = psum[i][q];
    }
    __syncthreads();
    if (tid < 256)
        part[(size_t)ct * M_TOT + rowbase + tid] =
            red[0][tid] + red[1][tid] + red[2][tid] + red[3][tid];
}

// softmax over L per batch; mask==0 -> -1e10; sums the NCT partials.
__global__ __launch_bounds__(512) void softmax_kernel(
        const float* __restrict__ part, const int* __restrict__ mask,
        float* __restrict__ out) {
    int b = blockIdx.x;
    int tid = threadIdx.x;
    int lane = tid & 63, w = tid >> 6;
    __shared__ float sred[8];

    float vals[4];
    #pragma unroll
    for (int p = 0; p < 4; ++p) {
        int row = b * LSEQ + tid + p * 512;
        float val = 0.f;
        #pragma unroll
        for (int q = 0; q < NCT; ++q) val += part[(size_t)q * M_TOT + row];
        vals[p] = (mask[row] == 0) ? NEG_INF_F : val;
    }
    float mx = fmaxf(fmaxf(vals[0], vals[1]), fmaxf(vals[2], vals[3]));
    #pragma unroll
    for (int m = 1; m < 64; m <<= 1) mx = fmaxf(mx, __shfl_xor(mx, m));
    if (lane == 0) sred[w] = mx;
    __syncthreads();
    float gmax = sred[0];
    #pragma unroll
    for (int i = 1; i < 8; ++i) gmax = fmaxf(gmax, sred[i]);

    float es[4]; float ssum = 0.f;
    #pragma unroll
    for (int p = 0; p < 4; ++p) { es[p] = expf(vals[p] - gmax); ssum += es[p]; }
    #pragma unroll
    for (int m = 1; m < 64; m <<= 1) ssum += __shfl_xor(ssum, m);
    __syncthreads();
    if (lane == 0) sred[w] = ssum;
    __syncthreads();
    float gsum = 0.f;
    #pragma unroll
    for (int i = 0; i < 8; ++i) gsum += sred[i];
    float inv = 1.f / gsum;
    #pragma unroll
    for (int p = 0; p < 4; ++p)
        out[b * LSEQ + tid + p * 512] = es[p] * inv;
}

extern "C" void kernel_launch(void* const* d_in, const int* in_sizes, int n_in,
                              void* d_out, int out_size, void* d_ws, size_t ws_size,
                              hipStream_t stream) {
    const float* enc    = (const float*)d_in[0];
    const int*   mask   = (const int*)  d_in[1];
    const float* v      = (const float*)d_in[2];
    const float* attn_w = (const float*)d_in[3];
    const float* attn_b = (const float*)d_in[4];
    const float* v_w    = (const float*)d_in[5];
    float* out = (float*)d_out;

    char* ws = (char*)d_ws;
    float* sdec = (float*)(ws + WS_SDEC_OFF);
    float* part = (float*)(ws + WS_PART_OFF);
    f16*   weT  = (f16*)  (ws + WS_WET_OFF);

    hipLaunchKernelGGL(wecvt_tiled, dim3(256),  dim3(256), 0, stream, attn_w, weT);
    hipLaunchKernelGGL(sdec_kernel, dim3(4096), dim3(256), 0, stream, v, attn_w, attn_b, sdec);
    hipLaunchKernelGGL(fused_gemm,  dim3(512),  dim3(512), 0, stream,
                       enc, weT, sdec, v_w, part);
    hipLaunchKernelGGL(softmax_kernel, dim3(16), dim3(512), 0, stream, part, mask, out);
}

// Round 13
// 214.378 us; speedup vs baseline: 1.5777x; 1.0049x over previous
//
#include <hip/hip_runtime.h>
#include <stdint.h>

#define LSEQ 2048
#define M_TOT 32768          // B*L
#define KDIM 2048            // 2H
#define NKT 64               // K tiles of 32
#define NCT 4                // col tiles of 256
#define NEG_INF_F (-10000000000.0f)

typedef _Float16 f16;
typedef f16 f16x8 __attribute__((ext_vector_type(8)));
typedef float f32x4 __attribute__((ext_vector_type(4)));

// ---------------- ws layout ----------------
// [0, 64K)      sdec f32[16][1024]
// [64K, 576K)   part f32[4][32768]
// [2M, 6M)      weT  tiled fp16 B [4 ct][64 kt][1024 granules x 16B]
#define WS_SDEC_OFF  0
#define WS_PART_OFF  (64u << 10)
#define WS_WET_OFF   (2u << 20)

#define SLOT_BYTES 49152     // A 32KB fp32 + B 16KB f16
#define BOFF 32768

__device__ inline void gload16(const void* g, void* l) {
    __builtin_amdgcn_global_load_lds(
        (const __attribute__((address_space(1))) void*)g,
        (__attribute__((address_space(3))) void*)l, 16, 0, 0);
}

// fast tanh(x)*s with sign fold
__device__ inline float tanh_mul(float x, float s) {
    float ax = __builtin_fabsf(x);
    float e  = __expf(-2.f * ax);
    float th = (1.f - e) * __builtin_amdgcn_rcpf(1.f + e);
    float sv = __uint_as_float(__float_as_uint(s) ^ (__float_as_uint(x) & 0x80000000u));
    return th * sv;
}

// W_e -> tiled fp16 B, 0-conflict swizzle (r5-verified): granule g: ct=g>>16,
// kt=(g>>10)&63, p=g&1023, row=p>>2, sl=(p&3)^((row>>1)&3).
__global__ __launch_bounds__(256) void wecvt_tiled(const float* __restrict__ attn_w,
                                                   f16* __restrict__ weT) {
    int g = blockIdx.x * 1024 + threadIdx.x;
    #pragma unroll
    for (int q = 0; q < 4; ++q, g += 256) {
        int ct  = g >> 16;
        int rem = g & 65535;
        int kt  = rem >> 10;
        int p   = rem & 1023;
        int row = p >> 2;
        int sl  = (p & 3) ^ ((row >> 1) & 3);
        const float* s = attn_w + (size_t)(ct * 256 + row) * 3072 + 1024 + kt * 32 + sl * 8;
        float4 a = *(const float4*)s;
        float4 b = *(const float4*)(s + 4);
        f16x8 h = { (f16)a.x,(f16)a.y,(f16)a.z,(f16)a.w,(f16)b.x,(f16)b.y,(f16)b.z,(f16)b.w };
        *(f16x8*)(weT + (size_t)g * 8) = h;
    }
}

// score_dec[b][h] = attn_b[h] + sum_k v[b][k] * attn_w[h][k]
__global__ void sdec_kernel(const float* __restrict__ v,
                            const float* __restrict__ attn_w,
                            const float* __restrict__ attn_b,
                            float* __restrict__ sdec) {
    int gid  = blockIdx.x * 4 + (threadIdx.x >> 6);
    int lane = threadIdx.x & 63;
    int b = gid >> 10;
    int h = gid & 1023;
    const float* vr = v + b * 1024;
    const float* wr = attn_w + (size_t)h * 3072;
    float s = 0.f;
    #pragma unroll 4
    for (int k = lane; k < 1024; k += 64) s += vr[k] * wr[k];
    #pragma unroll
    for (int m = 1; m < 64; m <<= 1) s += __shfl_xor(s, m);
    if (lane == 0) sdec[b * 1024 + h] = s + attn_b[h];
}

#define PH_OPEN  do { __builtin_amdgcn_sched_barrier(0); __builtin_amdgcn_s_barrier(); \
                      asm volatile("s_waitcnt lgkmcnt(0)" ::: "memory"); \
                      __builtin_amdgcn_sched_barrier(0); } while (0)
#define PH_CLOSE do { __builtin_amdgcn_sched_barrier(0); __builtin_amdgcn_s_barrier(); } while (0)

// ONE-PASS GEMM: 256x256 tile, 8 waves (2M x 4N), BK=32, 1 block/CU.
// A: raw fp32 enc staged via gload_lds, swizzled per-lane SOURCE, 3-slot ring.
//    A tile rows are 128B (=32 banks) -> row contributes nothing to bank index,
//    so the slot swizzle must be a FULL 3-bit row XOR: phys = logical ^ (row&7).
//    Reader lanes 0-7 then cover all 8 slots bijectively -> 0 conflicts.
// B: pre-tiled weT f16 (64B rows, r5 2-bit swizzle, verified 0-conflict).
// 2 phases/K-tile {ds_reads || stage; BAR; lgkm0; cvt; 16 MFMA; BAR};
// counted vmcnt(6) once per K-tile.
__global__ __launch_bounds__(512, 2) void fused_gemm(
        const float* __restrict__ enc,  // [32768][2048] fp32
        const f16* __restrict__ weT,    // [4 ct][64 kt][16KB]
        const float* __restrict__ sdec, // [16][1024]
        const float* __restrict__ vw,   // [1024]
        float* __restrict__ part)       // [NCT][32768]
{
    // chunked XCD remap: 512 blocks, 64/XCD; 4 ct-siblings of one rt adjacent
    const int logical = ((int)blockIdx.x & 7) * 64 + ((int)blockIdx.x >> 3);
    const int rt = logical >> 2;
    const int ct = logical & 3;

    const int tid = threadIdx.x;
    const int l15 = tid & 15;
    const int l4  = (tid >> 4) & 3;
    const int wv  = tid >> 6;        // 0..7
    const int wm  = wv >> 2;         // 0..1  (128 rows each)
    const int wn  = wv & 3;          // 0..3  (64 cols each)

    __shared__ char lds[3 * SLOT_BYTES];   // 147456 B
    __shared__ float red[4][256];

    const int rowbase = rt * 256;
    const char* bT = (const char*)weT + ((size_t)ct << 20);

    // ---- A staging: thread -> row (tid>>3)+64c, phys slot tid&7 ----
    // source logical slot = phys ^ (row&7); row&7 = (tid>>3)&7 (c-invariant)
    const int slA = (tid & 7) ^ ((tid >> 3) & 7);
    const float* aG = enc + (size_t)(rowbase + (tid >> 3)) * KDIM + slA * 4;

    // ---- A frag reads: row = wm*128 + i*16 + l15; phys0 = (2*l4) ^ (row&7) = (2*l4)^(l15&7)
    const int aoffB = (wm * 128 + l15) * 128 + ((((2 * l4) ^ (l15 & 7))) << 4);
    // ---- B frag reads (r5 layout): row 64B, phys = l4^((row>>1)&3)
    const int bro = BOFF + (wn * 64 + l15) * 64 + ((l4 ^ ((l15 >> 1) & 3)) << 4);

    f32x4 acc[8][4] = {};

    auto stageA = [&](int t, int slot) {
        const float* s = aG + (size_t)t * 32;
        char* d = lds + slot * SLOT_BYTES + tid * 16;
        gload16(s,              d);
        gload16(s +  64 * KDIM, d + 8192);
        gload16(s + 128 * KDIM, d + 16384);
        gload16(s + 192 * KDIM, d + 24576);
    };
    auto stageB = [&](int t, int slot) {
        const char* s = bT + ((size_t)t << 14) + tid * 16;
        char* d = lds + slot * SLOT_BYTES + BOFF + tid * 16;
        gload16(s, d); gload16(s + 8192, d + 8192);
    };
    auto mk = [](const float4& a, const float4& b) -> f16x8 {
        auto c0 = __builtin_amdgcn_cvt_pkrtz(a.x, a.y);
        auto c1 = __builtin_amdgcn_cvt_pkrtz(a.z, a.w);
        auto c2 = __builtin_amdgcn_cvt_pkrtz(b.x, b.y);
        auto c3 = __builtin_amdgcn_cvt_pkrtz(b.z, b.w);
        f16x8 r = { (f16)c0[0], (f16)c0[1], (f16)c1[0], (f16)c1[1],
                    (f16)c2[0], (f16)c2[1], (f16)c3[0], (f16)c3[1] };
        return r;
    };

    // ---- prologue: tiles 0,1 staged; drain tile 0 ----
    stageA(0, 0); stageB(0, 0);
    stageA(1, 1); stageB(1, 1);
    asm volatile("s_waitcnt vmcnt(6)" ::: "memory");
    __builtin_amdgcn_s_barrier();
    __builtin_amdgcn_sched_barrier(0);

    int rb = 0, sw = 2;   // read slot t%3, stage slot (t+2)%3
    #pragma unroll 1
    for (int t = 0; t < NKT; ++t) {
        const char* sb = lds + rb * SLOT_BYTES;
        float4 ra[4], rb4[4];
        f16x8 bf[4], fa[4];
        // ---------- phase 0: i=0..3 ----------
        #pragma unroll
        for (int ii = 0; ii < 4; ++ii) {
            const int o = aoffB + ii * 2048;
            ra[ii]  = *(const float4*)(sb + o);
            rb4[ii] = *(const float4*)(sb + (o ^ 16));
        }
        #pragma unroll
        for (int j = 0; j < 4; ++j) bf[j] = *(const f16x8*)(sb + bro + j * 1024);
        if (t + 2 < NKT) stageB(t + 2, sw);
        PH_OPEN;
        #pragma unroll
        for (int ii = 0; ii < 4; ++ii) fa[ii] = mk(ra[ii], rb4[ii]);
        __builtin_amdgcn_s_setprio(1);
        #pragma unroll
        for (int ii = 0; ii < 4; ++ii)
            #pragma unroll
            for (int j = 0; j < 4; ++j)
                acc[ii][j] = __builtin_amdgcn_mfma_f32_16x16x32_f16(fa[ii], bf[j], acc[ii][j], 0, 0, 0);
        __builtin_amdgcn_s_setprio(0);
        PH_CLOSE;
        // ---------- phase 1: i=4..7 ----------
        #pragma unroll
        for (int ii = 0; ii < 4; ++ii) {
            const int o = aoffB + (4 + ii) * 2048;
            ra[ii]  = *(const float4*)(sb + o);
            rb4[ii] = *(const float4*)(sb + (o ^ 16));
        }
        if (t + 2 < NKT) stageA(t + 2, sw);
        PH_OPEN;
        #pragma unroll
        for (int ii = 0; ii < 4; ++ii) fa[ii] = mk(ra[ii], rb4[ii]);
        __builtin_amdgcn_s_setprio(1);
        #pragma unroll
        for (int ii = 0; ii < 4; ++ii)
            #pragma unroll
            for (int j = 0; j < 4; ++j)
                acc[4 + ii][j] = __builtin_amdgcn_mfma_f32_16x16x32_f16(fa[ii], bf[j], acc[4 + ii][j], 0, 0, 0);
        __builtin_amdgcn_s_setprio(0);
        // counted vmcnt: tile t+1 must be fully landed for next iter;
        // leaves tile t+2's 6 loads in flight.
        if (t < NKT - 2) { asm volatile("s_waitcnt vmcnt(6)" ::: "memory"); }
        else             { asm volatile("s_waitcnt vmcnt(0)" ::: "memory"); }
        PH_CLOSE;
        rb = (rb == 2) ? 0 : rb + 1;
        sw = (sw == 2) ? 0 : sw + 1;
    }

    // ---------------- epilogue ----------------
    // C/D frag: col = l15, row = l4*4 + q; global row = rowbase + wm*128 + i*16 + l4*4 + q
    const int colbase = ct * 256;
    const int bidx = rt >> 3;

    float sd[4], vs[4];
    #pragma unroll
    for (int j = 0; j < 4; ++j) {
        const int col = colbase + wn * 64 + j * 16 + l15;
        sd[j] = sdec[bidx * 1024 + col];
        vs[j] = vw[col];
    }
    float psum[8][4] = {};
    #pragma unroll
    for (int i = 0; i < 8; ++i)
        #pragma unroll
        for (int j = 0; j < 4; ++j)
            #pragma unroll
            for (int q = 0; q < 4; ++q)
                psum[i][q] += tanh_mul(acc[i][j][q] + sd[j], vs[j]);

    #pragma unroll
    for (int i = 0; i < 8; ++i)
        #pragma unroll
        for (int q = 0; q < 4; ++q) {
            float s = psum[i][q];
            s += __shfl_xor(s, 1); s += __shfl_xor(s, 2);
            s += __shfl_xor(s, 4); s += __shfl_xor(s, 8);
            psum[i][q] = s;
        }

    __syncthreads();
    if (l15 == 0) {
        #pragma unroll
        for (int i = 0; i < 8; ++i)
            #pragma unroll
            for (int q = 0; q < 4; ++q)
                red[wn][wm * 128 + i * 16 + l4 * 4 + q] = psum[i][q];
    }
    __syncthreads();
    if (tid < 256)
        part[(size_t)ct * M_TOT + rowbase + tid] =
            red[0][tid] + red[1][tid] + red[2][tid] + red[3][tid];
}

// softmax over L per batch; mask==0 -> -1e10; sums the NCT partials.
__global__ __launch_bounds__(512) void softmax_kernel(
        const float* __restrict__ part, const int* __restrict__ mask,
        float* __restrict__ out) {
    int b = blockIdx.x;
    int tid = threadIdx.x;
    int lane = tid & 63, w = tid >> 6;
    __shared__ float sred[8];

    float vals[4];
    #pragma unroll
    for (int p = 0; p < 4; ++p) {
        int row = b * LSEQ + tid + p * 512;
        float val = 0.f;
        #pragma unroll
        for (int q = 0; q < NCT; ++q) val += part[(size_t)q * M_TOT + row];
        vals[p] = (mask[row] == 0) ? NEG_INF_F : val;
    }
    float mx = fmaxf(fmaxf(vals[0], vals[1]), fmaxf(vals[2], vals[3]));
    #pragma unroll
    for (int m = 1; m < 64; m <<= 1) mx = fmaxf(mx, __shfl_xor(mx, m));
    if (lane == 0) sred[w] = mx;
    __syncthreads();
    float gmax = sred[0];
    #pragma unroll
    for (int i = 1; i < 8; ++i) gmax = fmaxf(gmax, sred[i]);

    float es[4]; float ssum = 0.f;
    #pragma unroll
    for (int p = 0; p < 4; ++p) { es[p] = expf(vals[p] - gmax); ssum += es[p]; }
    #pragma unroll
    for (int m = 1; m < 64; m <<= 1) ssum += __shfl_xor(ssum, m);
    __syncthreads();
    if (lane == 0) sred[w] = ssum;
    __syncthreads();
    float gsum = 0.f;
    #pragma unroll
    for (int i = 0; i < 8; ++i) gsum += sred[i];
    float inv = 1.f / gsum;
    #pragma unroll
    for (int p = 0; p < 4; ++p)
        out[b * LSEQ + tid + p * 512] = es[p] * inv;
}

extern "C" void kernel_launch(void* const* d_in, const int* in_sizes, int n_in,
                              void* d_out, int out_size, void* d_ws, size_t ws_size,
                              hipStream_t stream) {
    const float* enc    = (const float*)d_in[0];
    const int*   mask   = (const int*)  d_in[1];
    const float* v      = (const float*)d_in[2];
    const float* attn_w = (const float*)d_in[3];
    const float* attn_b = (const float*)d_in[4];
    const float* v_w    = (const float*)d_in[5];
    float* out = (float*)d_out;

    char* ws = (char*)d_ws;
    float* sdec = (float*)(ws + WS_SDEC_OFF);
    float* part = (float*)(ws + WS_PART_OFF);
    f16*   weT  = (f16*)  (ws + WS_WET_OFF);

    hipLaunchKernelGGL(wecvt_tiled, dim3(256),  dim3(256), 0, stream, attn_w, weT);
    hipLaunchKernelGGL(sdec_kernel, dim3(4096), dim3(256), 0, stream, v, attn_w, attn_b, sdec);
    hipLaunchKernelGGL(fused_gemm,  dim3(512),  dim3(512), 0, stream,
                       enc, weT, sdec, v_w, part);
    hipLaunchKernelGGL(softmax_kernel, dim3(16), dim3(512), 0, stream, part, mask, out);
}

// Round 14
// 176.957 us; speedup vs baseline: 1.9113x; 1.2115x over previous
//
#include <hip/hip_runtime.h>
#include <stdint.h>

#define LSEQ 2048
#define M_TOT 32768          // B*L
#define KDIM 2048            // 2H
#define NKT 64               // K tiles of 32
#define NCT 4                // col tiles of 256
#define NEG_INF_F (-10000000000.0f)

typedef _Float16 f16;
typedef f16 f16x8 __attribute__((ext_vector_type(8)));
typedef float f32x4 __attribute__((ext_vector_type(4)));

// ---------------- ws layout ----------------
// [0, 64K)      sdec f32[16][1024]
// [64K, 576K)   part f32[4][32768]
// [2M, 6M)      weT  tiled fp16 B [4 ct][64 kt][1024 granules x 16B]
#define WS_SDEC_OFF  0
#define WS_PART_OFF  (64u << 10)
#define WS_WET_OFF   (2u << 20)

// LDS: A f16 2 slots x 16KB, B f16 3 slots x 16KB
#define A_SLOT(s) ((s) * 16384)
#define B_SLOT(s) (32768 + (s) * 16384)

__device__ inline void gload16(const void* g, void* l) {
    __builtin_amdgcn_global_load_lds(
        (const __attribute__((address_space(1))) void*)g,
        (__attribute__((address_space(3))) void*)l, 16, 0, 0);
}

// fast tanh(x)*s with sign fold
__device__ inline float tanh_mul(float x, float s) {
    float ax = __builtin_fabsf(x);
    float e  = __expf(-2.f * ax);
    float th = (1.f - e) * __builtin_amdgcn_rcpf(1.f + e);
    float sv = __uint_as_float(__float_as_uint(s) ^ (__float_as_uint(x) & 0x80000000u));
    return th * sv;
}

// W_e -> tiled fp16 B, 0-conflict swizzle (r5-verified): granule g: ct=g>>16,
// kt=(g>>10)&63, p=g&1023, row=p>>2, sl=(p&3)^((row>>1)&3).
__global__ __launch_bounds__(256) void wecvt_tiled(const float* __restrict__ attn_w,
                                                   f16* __restrict__ weT) {
    int g = blockIdx.x * 1024 + threadIdx.x;
    #pragma unroll
    for (int q = 0; q < 4; ++q, g += 256) {
        int ct  = g >> 16;
        int rem = g & 65535;
        int kt  = rem >> 10;
        int p   = rem & 1023;
        int row = p >> 2;
        int sl  = (p & 3) ^ ((row >> 1) & 3);
        const float* s = attn_w + (size_t)(ct * 256 + row) * 3072 + 1024 + kt * 32 + sl * 8;
        float4 a = *(const float4*)s;
        float4 b = *(const float4*)(s + 4);
        f16x8 h = { (f16)a.x,(f16)a.y,(f16)a.z,(f16)a.w,(f16)b.x,(f16)b.y,(f16)b.z,(f16)b.w };
        *(f16x8*)(weT + (size_t)g * 8) = h;
    }
}

// score_dec[b][h] = attn_b[h] + sum_k v[b][k] * attn_w[h][k]
__global__ void sdec_kernel(const float* __restrict__ v,
                            const float* __restrict__ attn_w,
                            const float* __restrict__ attn_b,
                            float* __restrict__ sdec) {
    int gid  = blockIdx.x * 4 + (threadIdx.x >> 6);
    int lane = threadIdx.x & 63;
    int b = gid >> 10;
    int h = gid & 1023;
    const float* vr = v + b * 1024;
    const float* wr = attn_w + (size_t)h * 3072;
    float s = 0.f;
    #pragma unroll 4
    for (int k = lane; k < 1024; k += 64) s += vr[k] * wr[k];
    #pragma unroll
    for (int m = 1; m < 64; m <<= 1) s += __shfl_xor(s, m);
    if (lane == 0) sdec[b * 1024 + h] = s + attn_b[h];
}

#define PH_OPEN  do { __builtin_amdgcn_sched_barrier(0); __builtin_amdgcn_s_barrier(); \
                      asm volatile("s_waitcnt lgkmcnt(0)" ::: "memory"); \
                      __builtin_amdgcn_sched_barrier(0); } while (0)
#define PH_CLOSE do { __builtin_amdgcn_sched_barrier(0); __builtin_amdgcn_s_barrier(); } while (0)

// ONE-PASS GEMM, f16 LDS both operands: 256x256 tile, 8 waves (2M x 4N), BK=32.
// A: fp32 global -> regs (coalesced 128B row-segments, issued 1 FULL ITERATION
//    before use) -> cvt_pkrtz -> swizzled ds_write_b128 into 2-slot f16 ring.
// B: pre-tiled weT f16 via gload_lds, 3-slot ring, counted vmcnt(6).
// 2 phases/K-tile {ds_reads || issue/cvt/write; BAR; lgkm0; 16 MFMA; BAR}.
__global__ __launch_bounds__(512, 2) void fused_gemm(
        const float* __restrict__ enc,  // [32768][2048] fp32
        const f16* __restrict__ weT,    // [4 ct][64 kt][16KB]
        const float* __restrict__ sdec, // [16][1024]
        const float* __restrict__ vw,   // [1024]
        float* __restrict__ part)       // [NCT][32768]
{
    // chunked XCD remap: 512 blocks, 64/XCD; 4 ct-siblings of one rt adjacent
    const int logical = ((int)blockIdx.x & 7) * 64 + ((int)blockIdx.x >> 3);
    const int rt = logical >> 2;
    const int ct = logical & 3;

    const int tid = threadIdx.x;
    const int l15 = tid & 15;
    const int l4  = (tid >> 4) & 3;
    const int wv  = tid >> 6;        // 0..7
    const int wm  = wv >> 2;         // 0..1  (128 rows each)
    const int wn  = wv & 3;          // 0..3  (64 cols each)

    __shared__ char lds[32768 + 49152];   // A 2x16KB + B 3x16KB
    __shared__ float red[4][256];

    const int rowbase = rt * 256;
    const char* bT = (const char*)weT + ((size_t)ct << 20);

    // ---- A staging: thread -> row ar=tid>>1, k-half ah=tid&1 (16 floats) ----
    const int ar_ = tid >> 1;
    const int ah  = tid & 1;
    const float* aG = enc + (size_t)(rowbase + ar_) * KDIM + ah * 16;
    // write slots s0=2ah, s0+1; phys = s ^ ((ar>>1)&3); 64B rows
    const int aswz = (ar_ >> 1) & 3;
    const int awb0 = ar_ * 64 + (((2 * ah)     ^ aswz) << 4);
    const int awb1 = ar_ * 64 + (((2 * ah + 1) ^ aswz) << 4);

    // ---- frag reads (r5-verified 0-conflict): row 64B, phys = l4^((row>>1)&3)
    const int fswz = (l4 ^ ((l15 >> 1) & 3)) << 4;
    const int aro = (wm * 128 + l15) * 64 + fswz;   // + i*1024, i=0..7
    const int bro = (wn * 64  + l15) * 64 + fswz;   // + j*1024, j=0..3

    f32x4 acc[8][4] = {};

    auto loadAreg = [&](float4 (&s)[4], int t) {
        const float* p = aG + (size_t)t * 32;
        s[0] = *(const float4*)(p);
        s[1] = *(const float4*)(p + 4);
        s[2] = *(const float4*)(p + 8);
        s[3] = *(const float4*)(p + 12);
    };
    auto writeA = [&](const float4 (&s)[4], int slot) {
        char* d = lds + A_SLOT(slot);
        auto c0 = __builtin_amdgcn_cvt_pkrtz(s[0].x, s[0].y);
        auto c1 = __builtin_amdgcn_cvt_pkrtz(s[0].z, s[0].w);
        auto c2 = __builtin_amdgcn_cvt_pkrtz(s[1].x, s[1].y);
        auto c3 = __builtin_amdgcn_cvt_pkrtz(s[1].z, s[1].w);
        auto c4 = __builtin_amdgcn_cvt_pkrtz(s[2].x, s[2].y);
        auto c5 = __builtin_amdgcn_cvt_pkrtz(s[2].z, s[2].w);
        auto c6 = __builtin_amdgcn_cvt_pkrtz(s[3].x, s[3].y);
        auto c7 = __builtin_amdgcn_cvt_pkrtz(s[3].z, s[3].w);
        f16x8 h0 = { (f16)c0[0],(f16)c0[1],(f16)c1[0],(f16)c1[1],
                     (f16)c2[0],(f16)c2[1],(f16)c3[0],(f16)c3[1] };
        f16x8 h1 = { (f16)c4[0],(f16)c4[1],(f16)c5[0],(f16)c5[1],
                     (f16)c6[0],(f16)c6[1],(f16)c7[0],(f16)c7[1] };
        *(f16x8*)(d + awb0) = h0;
        *(f16x8*)(d + awb1) = h1;
    };
    auto stageB = [&](int t, int slot) {
        const char* s = bT + ((size_t)t << 14) + tid * 16;
        char* d = lds + B_SLOT(slot) + tid * 16;
        gload16(s, d); gload16(s + 8192, d + 8192);
    };

    int arS = 0, brS = 0, bwS = 2;

    auto body = [&](int t, float4 (&sIss)[4], float4 (&sCvt)[4]) {
        const char* sa = lds + A_SLOT(arS);
        const char* sb = lds + B_SLOT(brS);
        f16x8 fa[4], bf[4];
        // ---------- phase 0: i=0..3 ----------
        #pragma unroll
        for (int ii = 0; ii < 4; ++ii) fa[ii] = *(const f16x8*)(sa + aro + ii * 1024);
        #pragma unroll
        for (int j = 0; j < 4; ++j)  bf[j]  = *(const f16x8*)(sb + bro + j * 1024);
        if (t + 2 < NKT) loadAreg(sIss, t + 2);
        PH_OPEN;
        __builtin_amdgcn_s_setprio(1);
        #pragma unroll
        for (int ii = 0; ii < 4; ++ii)
            #pragma unroll
            for (int j = 0; j < 4; ++j)
                acc[ii][j] = __builtin_amdgcn_mfma_f32_16x16x32_f16(fa[ii], bf[j], acc[ii][j], 0, 0, 0);
        __builtin_amdgcn_s_setprio(0);
        PH_CLOSE;
        // ---------- phase 1: i=4..7 ----------
        #pragma unroll
        for (int ii = 0; ii < 4; ++ii) fa[ii] = *(const f16x8*)(sa + aro + (4 + ii) * 1024);
        if (t + 1 < NKT) writeA(sCvt, arS ^ 1);   // regs issued 1 iter ago; auto-vmcnt free
        if (t + 2 < NKT) stageB(t + 2, bwS);
        PH_OPEN;
        __builtin_amdgcn_s_setprio(1);
        #pragma unroll
        for (int ii = 0; ii < 4; ++ii)
            #pragma unroll
            for (int j = 0; j < 4; ++j)
                acc[4 + ii][j] = __builtin_amdgcn_mfma_f32_16x16x32_f16(fa[ii], bf[j], acc[4 + ii][j], 0, 0, 0);
        __builtin_amdgcn_s_setprio(0);
        // counted vmcnt: B(t+1) (issued iter t-1) must be landed for next iter;
        // leaves A-regs(t+2) 4 + B(t+2) 2 in flight.
        if (t < NKT - 3) { asm volatile("s_waitcnt vmcnt(6)" ::: "memory"); }
        else             { asm volatile("s_waitcnt vmcnt(0)" ::: "memory"); }
        PH_CLOSE;
        arS ^= 1;
        brS = (brS == 2) ? 0 : brS + 1;
        bwS = (bwS == 2) ? 0 : bwS + 1;
    };

    float4 sEven[4], sOdd[4];
    // ---- prologue: A(0) -> slot0 (direct), A(1) -> regs (held), B(0),B(1) ----
    loadAreg(sEven, 0);
    writeA(sEven, 0);                 // compiler waits sEven's loads
    loadAreg(sOdd, 1);                // consumed at iter 0 phase 1 -> slot 1
    stageB(0, 0); stageB(1, 1);
    asm volatile("s_waitcnt lgkmcnt(0)" ::: "memory");   // A(0) ds_writes drained
    asm volatile("s_waitcnt vmcnt(2)" ::: "memory");     // B(0) landed (sOdd+B1 left... drains sOdd4+B0)
    __builtin_amdgcn_s_barrier();
    __builtin_amdgcn_sched_barrier(0);

    #pragma unroll 1
    for (int tt = 0; tt < NKT; tt += 2) {
        body(tt,     sEven, sOdd);    // issues A(tt+2)->sEven, cvt sOdd -> tile tt+1
        body(tt + 1, sOdd,  sEven);   // issues A(tt+3)->sOdd,  cvt sEven -> tile tt+2
    }

    // ---------------- epilogue ----------------
    // C/D frag: col = l15, row = l4*4 + q; global row = rowbase + wm*128 + i*16 + l4*4 + q
    const int colbase = ct * 256;
    const int bidx = rt >> 3;

    float sd[4], vs[4];
    #pragma unroll
    for (int j = 0; j < 4; ++j) {
        const int col = colbase + wn * 64 + j * 16 + l15;
        sd[j] = sdec[bidx * 1024 + col];
        vs[j] = vw[col];
    }
    float psum[8][4] = {};
    #pragma unroll
    for (int i = 0; i < 8; ++i)
        #pragma unroll
        for (int j = 0; j < 4; ++j)
            #pragma unroll
            for (int q = 0; q < 4; ++q)
                psum[i][q] += tanh_mul(acc[i][j][q] + sd[j], vs[j]);

    #pragma unroll
    for (int i = 0; i < 8; ++i)
        #pragma unroll
        for (int q = 0; q < 4; ++q) {
            float s = psum[i][q];
            s += __shfl_xor(s, 1); s += __shfl_xor(s, 2);
            s += __shfl_xor(s, 4); s += __shfl_xor(s, 8);
            psum[i][q] = s;
        }

    __syncthreads();
    if (l15 == 0) {
        #pragma unroll
        for (int i = 0; i < 8; ++i)
            #pragma unroll
            for (int q = 0; q < 4; ++q)
                red[wn][wm * 128 + i * 16 + l4 * 4 + q] = psum[i][q];
    }
    __syncthreads();
    if (tid < 256)
        part[(size_t)ct * M_TOT + rowbase + tid] =
            red[0][tid] + red[1][tid] + red[2][tid] + red[3][tid];
}

// softmax over L per batch; mask==0 -> -1e10; sums the NCT partials.
__global__ __launch_bounds__(512) void softmax_kernel(
        const float* __restrict__ part, const int* __restrict__ mask,
        float* __restrict__ out) {
    int b = blockIdx.x;
    int tid = threadIdx.x;
    int lane = tid & 63, w = tid >> 6;
    __shared__ float sred[8];

    float vals[4];
    #pragma unroll
    for (int p = 0; p < 4; ++p) {
        int row = b * LSEQ + tid + p * 512;
        float val = 0.f;
        #pragma unroll
        for (int q = 0; q < NCT; ++q) val += part[(size_t)q * M_TOT + row];
        vals[p] = (mask[row] == 0) ? NEG_INF_F : val;
    }
    float mx = fmaxf(fmaxf(vals[0], vals[1]), fmaxf(vals[2], vals[3]));
    #pragma unroll
    for (int m = 1; m < 64; m <<= 1) mx = fmaxf(mx, __shfl_xor(mx, m));
    if (lane == 0) sred[w] = mx;
    __syncthreads();
    float gmax = sred[0];
    #pragma unroll
    for (int i = 1; i < 8; ++i) gmax = fmaxf(gmax, sred[i]);

    float es[4]; float ssum = 0.f;
    #pragma unroll
    for (int p = 0; p < 4; ++p) { es[p] = expf(vals[p] - gmax); ssum += es[p]; }
    #pragma unroll
    for (int m = 1; m < 64; m <<= 1) ssum += __shfl_xor(ssum, m);
    __syncthreads();
    if (lane == 0) sred[w] = ssum;
    __syncthreads();
    float gsum = 0.f;
    #pragma unroll
    for (int i = 0; i < 8; ++i) gsum += sred[i];
    float inv = 1.f / gsum;
    #pragma unroll
    for (int p = 0; p < 4; ++p)
        out[b * LSEQ + tid + p * 512] = es[p] * inv;
}

extern "C" void kernel_launch(void* const* d_in, const int* in_sizes, int n_in,
                              void* d_out, int out_size, void* d_ws, size_t ws_size,
                              hipStream_t stream) {
    const float* enc    = (const float*)d_in[0];
    const int*   mask   = (const int*)  d_in[1];
    const float* v      = (const float*)d_in[2];
    const float* attn_w = (const float*)d_in[3];
    const float* attn_b = (const float*)d_in[4];
    const float* v_w    = (const float*)d_in[5];
    float* out = (float*)d_out;

    char* ws = (char*)d_ws;
    float* sdec = (float*)(ws + WS_SDEC_OFF);
    float* part = (float*)(ws + WS_PART_OFF);
    f16*   weT  = (f16*)  (ws + WS_WET_OFF);

    hipLaunchKernelGGL(wecvt_tiled, dim3(256),  dim3(256), 0, stream, attn_w, weT);
    hipLaunchKernelGGL(sdec_kernel, dim3(4096), dim3(256), 0, stream, v, attn_w, attn_b, sdec);
    hipLaunchKernelGGL(fused_gemm,  dim3(512),  dim3(512), 0, stream,
                       enc, weT, sdec, v_w, part);
    hipLaunchKernelGGL(softmax_kernel, dim3(16), dim3(512), 0, stream, part, mask, out);
}